// Round 1
// baseline (185.225 us; speedup 1.0000x reference)
//
#include <hip/hip_runtime.h>

#define D_    2560
#define NH_   8
#define NKV_  4
#define HD_   256
#define FFN_  10240
#define QD_   2048
#define CTX_  4096
#define EPSF  1e-6f
#define LCHUNKS 16
#define LCHUNK  256

__device__ __forceinline__ float wave_red_sum(float v) {
#pragma unroll
    for (int o = 32; o > 0; o >>= 1) v += __shfl_down(v, o, 64);
    return v;
}

// block of 256 threads (4 waves)
__device__ __forceinline__ float block_red_sum(float v) {
    __shared__ float s[4];
    __shared__ float tot;
    int lane = threadIdx.x & 63, w = threadIdx.x >> 6;
    v = wave_red_sum(v);
    if (lane == 0) s[w] = v;
    __syncthreads();
    if (threadIdx.x == 0) tot = s[0] + s[1] + s[2] + s[3];
    __syncthreads();
    return tot;
}

__device__ __forceinline__ float block_red_max(float v) {
    __shared__ float s[4];
    __shared__ float tot;
    int lane = threadIdx.x & 63, w = threadIdx.x >> 6;
#pragma unroll
    for (int o = 32; o > 0; o >>= 1) v = fmaxf(v, __shfl_down(v, o, 64));
    if (lane == 0) s[w] = v;
    __syncthreads();
    if (threadIdx.x == 0) tot = fmaxf(fmaxf(s[0], s[1]), fmaxf(s[2], s[3]));
    __syncthreads();
    return tot;
}

// out1 = (res?) res + rms(a)*(1+w1);   optionally out2 = rms(out1)*(1+w2)
// one block, 256 threads, n fixed = D_
__global__ void k_res_rms(const float* __restrict__ res,
                          const float* __restrict__ a,
                          const float* __restrict__ w1, float* __restrict__ out1,
                          const float* __restrict__ w2, float* __restrict__ out2) {
    const int K = D_ / 256;
    int t = threadIdx.x;
    float va[K];
    float ss = 0.f;
#pragma unroll
    for (int k = 0; k < K; k++) {
        int i = t + k * 256;
        va[k] = a[i];
        ss += va[k] * va[k];
    }
    float tot = block_red_sum(ss);
    float rs = rsqrtf(tot / (float)D_ + EPSF);
    float vo[K];
    float ss2 = 0.f;
#pragma unroll
    for (int k = 0; k < K; k++) {
        int i = t + k * 256;
        float r = res ? res[i] : 0.f;
        vo[k] = r + va[k] * rs * (1.f + w1[i]);
        out1[i] = vo[k];
        ss2 += vo[k] * vo[k];
    }
    if (out2) {
        float tot2 = block_red_sum(ss2);
        float rs2 = rsqrtf(tot2 / (float)D_ + EPSF);
#pragma unroll
        for (int k = 0; k < K; k++) {
            int i = t + k * 256;
            out2[i] = vo[k] * rs2 * (1.f + w2[i]);
        }
    }
}

// per-head q-norm (no weight) + RoPE.  grid = NH_, block = HD_ (=256)
__global__ void k_qnorm_rope(const float* __restrict__ qraw,
                             const float* __restrict__ cosv,
                             const float* __restrict__ sinv,
                             float* __restrict__ qout) {
    __shared__ float qn[HD_];
    int h = blockIdx.x, d = threadIdx.x;
    float v = qraw[h * HD_ + d];
    float tot = block_red_sum(v * v);
    float rs = rsqrtf(tot / (float)HD_ + EPSF);
    float n = v * rs;
    qn[d] = n;
    __syncthreads();
    float rot = (d < HD_ / 2) ? -qn[d + HD_ / 2] : qn[d - HD_ / 2];
    qout[h * HD_ + d] = n * cosv[d] + rot * sinv[d];
}

// y[row] = dot(W[row,:], x).  wave per row, block=256 (4 rows/block)
template <int COLS>
__global__ void k_gemv(const float* __restrict__ W, const float* __restrict__ x,
                       float* __restrict__ y, int rows) {
    int lane = threadIdx.x & 63;
    int row = blockIdx.x * 4 + (threadIdx.x >> 6);
    if (row >= rows) return;
    const float4* Wr = (const float4*)(W + (size_t)row * COLS);
    const float4* x4 = (const float4*)x;
    float acc = 0.f;
#pragma unroll 4
    for (int j = lane; j < COLS / 4; j += 64) {
        float4 w = Wr[j], xx = x4[j];
        acc += w.x * xx.x + w.y * xx.y + w.z * xx.z + w.w * xx.w;
    }
    acc = wave_red_sum(acc);
    if (lane == 0) y[row] = acc;
}

// scores for both q-heads of one kv head.  grid=(NKV_, LCHUNKS), block=256
__global__ void k_scores(const float* __restrict__ Kc, const float* __restrict__ q,
                         const float* __restrict__ mask, float* __restrict__ s) {
    int kvh = blockIdx.x, chunk = blockIdx.y;
    int lane = threadIdx.x & 63, w = threadIdx.x >> 6;
    int h0 = 2 * kvh, h1 = h0 + 1;
    const float4* q4 = (const float4*)q;
    float4 q0 = q4[h0 * 64 + lane];
    float4 q1 = q4[h1 * 64 + lane];
    int lbase = chunk * LCHUNK + w * 64;
    for (int i = 0; i < 64; i++) {
        int l = lbase + i;
        const float4* Kr = (const float4*)(Kc + ((size_t)kvh * CTX_ + l) * HD_);
        float4 kk = Kr[lane];
        float d0 = kk.x * q0.x + kk.y * q0.y + kk.z * q0.z + kk.w * q0.w;
        float d1 = kk.x * q1.x + kk.y * q1.y + kk.z * q1.z + kk.w * q1.w;
#pragma unroll
        for (int o = 32; o > 0; o >>= 1) {
            d0 += __shfl_down(d0, o, 64);
            d1 += __shfl_down(d1, o, 64);
        }
        if (lane == 0) {
            float m = mask[l];
            s[(size_t)h0 * CTX_ + l] = d0 + m;
            s[(size_t)h1 * CTX_ + l] = d1 + m;
        }
    }
}

// in-place softmax over CTX_ per head.  grid=NH_, block=256
__global__ void k_softmax(float* __restrict__ s) {
    int h = blockIdx.x, t = threadIdx.x;
    float* sh = s + (size_t)h * CTX_;
    float m = -1e30f;
    for (int l = t; l < CTX_; l += 256) m = fmaxf(m, sh[l]);
    m = block_red_max(m);
    float sum = 0.f;
    for (int l = t; l < CTX_; l += 256) {
        float e = expf(sh[l] - m);
        sh[l] = e;
        sum += e;
    }
    sum = block_red_sum(sum);
    float inv = 1.f / sum;
    for (int l = t; l < CTX_; l += 256) sh[l] *= inv;
}

// weighted V partials: V read once per kv head, used for both q heads.
// grid=(NKV_, LCHUNKS), block=HD_ (=256), thread d = output dim
__global__ void k_wv(const float* __restrict__ V, const float* __restrict__ p,
                     float* __restrict__ part) {
    int kvh = blockIdx.x, chunk = blockIdx.y, d = threadIdx.x;
    int h0 = 2 * kvh, h1 = h0 + 1;
    __shared__ float p0[LCHUNK], p1[LCHUNK];
    int l0 = chunk * LCHUNK;
    p0[d] = p[(size_t)h0 * CTX_ + l0 + d];
    p1[d] = p[(size_t)h1 * CTX_ + l0 + d];
    __syncthreads();
    const float* Vb = V + ((size_t)kvh * CTX_ + l0) * HD_;
    float a0 = 0.f, a1 = 0.f;
    for (int li = 0; li < LCHUNK; li++) {
        float v = Vb[(size_t)li * HD_ + d];
        a0 += p0[li] * v;
        a1 += p1[li] * v;
    }
    part[((h0 * LCHUNKS) + chunk) * HD_ + d] = a0;
    part[((h1 * LCHUNKS) + chunk) * HD_ + d] = a1;
}

// a[h*HD+d] = sum over chunks.  grid=NH_, block=HD_
__global__ void k_reduce_a(const float* __restrict__ part, float* __restrict__ a) {
    int h = blockIdx.x, d = threadIdx.x;
    float s = 0.f;
#pragma unroll
    for (int c = 0; c < LCHUNKS; c++) s += part[((h * LCHUNKS) + c) * HD_ + d];
    a[h * HD_ + d] = s;
}

// gu[row] = gelu_tanh(dot(Wg[row],h)) * dot(Wu[row],h).  wave per row.
__global__ void k_geglu(const float* __restrict__ Wg, const float* __restrict__ Wu,
                        const float* __restrict__ h, float* __restrict__ gu) {
    int lane = threadIdx.x & 63;
    int row = blockIdx.x * 4 + (threadIdx.x >> 6);
    const float4* g4 = (const float4*)(Wg + (size_t)row * D_);
    const float4* u4 = (const float4*)(Wu + (size_t)row * D_);
    const float4* x4 = (const float4*)h;
    float ag = 0.f, au = 0.f;
#pragma unroll 2
    for (int j = lane; j < D_ / 4; j += 64) {
        float4 xx = x4[j];
        float4 g = g4[j];
        float4 u = u4[j];
        ag += g.x * xx.x + g.y * xx.y + g.z * xx.z + g.w * xx.w;
        au += u.x * xx.x + u.y * xx.y + u.z * xx.z + u.w * xx.w;
    }
#pragma unroll
    for (int o = 32; o > 0; o >>= 1) {
        ag += __shfl_down(ag, o, 64);
        au += __shfl_down(au, o, 64);
    }
    if (lane == 0) {
        float x = ag;
        float t = tanhf(0.7978845608028654f * (x + 0.044715f * x * x * x));
        gu[row] = 0.5f * x * (1.f + t) * au;
    }
}

extern "C" void kernel_launch(void* const* d_in, const int* in_sizes, int n_in,
                              void* d_out, int out_size, void* d_ws, size_t ws_size,
                              hipStream_t stream) {
    const float* x     = (const float*)d_in[0];
    const float* cosv  = (const float*)d_in[1];
    const float* sinv  = (const float*)d_in[2];
    const float* mask  = (const float*)d_in[3];
    const float* cK    = (const float*)d_in[4];
    const float* cV    = (const float*)d_in[5];
    // d_in[6] = ctx_len (== CTX_)
    const float* w_in  = (const float*)d_in[7];
    const float* w_pa  = (const float*)d_in[8];
    const float* w_pf  = (const float*)d_in[9];
    const float* w_pff = (const float*)d_in[10];
    const float* Wq    = (const float*)d_in[11];
    const float* Wo    = (const float*)d_in[12];
    const float* Wg    = (const float*)d_in[13];
    const float* Wu    = (const float*)d_in[14];
    const float* Wd    = (const float*)d_in[15];

    float* ws   = (float*)d_ws;
    float* h    = ws;           // 2560
    float* qraw = ws + 2560;    // 2048
    float* q    = ws + 4608;    // 2048
    float* sc   = ws + 6656;    // 8*4096 = 32768
    float* part = ws + 39424;   // 8*16*256 = 32768
    float* a    = ws + 72192;   // 2048
    float* ao   = ws + 74240;   // 2560
    float* x2   = ws + 76800;   // 2560
    float* h2   = ws + 79360;   // 2560
    float* gu   = ws + 81920;   // 10240
    float* ffn  = ws + 92160;   // 2560
    float* out  = (float*)d_out;

    // h = rmsnorm(x, w_in)
    k_res_rms<<<1, 256, 0, stream>>>(nullptr, x, w_in, h, nullptr, nullptr);
    // qraw = h @ Wq.T
    k_gemv<D_><<<QD_ / 4, 256, 0, stream>>>(Wq, h, qraw, QD_);
    // q = rope(qnorm(qraw))
    k_qnorm_rope<<<NH_, HD_, 0, stream>>>(qraw, cosv, sinv, q);
    // scores
    k_scores<<<dim3(NKV_, LCHUNKS), 256, 0, stream>>>(cK, q, mask, sc);
    // softmax in-place
    k_softmax<<<NH_, 256, 0, stream>>>(sc);
    // weighted V partials, then reduce to a
    k_wv<<<dim3(NKV_, LCHUNKS), HD_, 0, stream>>>(cV, sc, part);
    k_reduce_a<<<NH_, HD_, 0, stream>>>(part, a);
    // ao = a @ Wo.T
    k_gemv<QD_><<<D_ / 4, 256, 0, stream>>>(Wo, a, ao, D_);
    // x2 = x + rms(ao)*(1+w_pa);  h2 = rms(x2)*(1+w_pf)
    k_res_rms<<<1, 256, 0, stream>>>(x, ao, w_pa, x2, w_pf, h2);
    // gu = gelu(h2@Wg.T) * (h2@Wu.T)
    k_geglu<<<FFN_ / 4, 256, 0, stream>>>(Wg, Wu, h2, gu);
    // ffn = gu @ Wd.T
    k_gemv<FFN_><<<D_ / 4, 256, 0, stream>>>(Wd, gu, ffn, D_);
    // out = x2 + rms(ffn)*(1+w_pff)
    k_res_rms<<<1, 256, 0, stream>>>(x2, ffn, w_pff, out, nullptr, nullptr);
}

// Round 2
// 184.644 us; speedup vs baseline: 1.0031x; 1.0031x over previous
//
#include <hip/hip_runtime.h>

#define D_    2560
#define NH_   8
#define NKV_  4
#define HD_   256
#define FFN_  10240
#define QD_   2048
#define CTX_  4096
#define EPSF  1e-6f
#define LCHUNKS 16
#define LCHUNK  256

__device__ __forceinline__ float wave_red_sum(float v) {
#pragma unroll
    for (int o = 32; o > 0; o >>= 1) v += __shfl_down(v, o, 64);
    return v;
}

// block of 256 threads (4 waves)
__device__ __forceinline__ float block_red_sum(float v) {
    __shared__ float s[4];
    __shared__ float tot;
    int lane = threadIdx.x & 63, w = threadIdx.x >> 6;
    v = wave_red_sum(v);
    if (lane == 0) s[w] = v;
    __syncthreads();
    if (threadIdx.x == 0) tot = s[0] + s[1] + s[2] + s[3];
    __syncthreads();
    return tot;
}

__device__ __forceinline__ float block_red_max(float v) {
    __shared__ float s[4];
    __shared__ float tot;
    int lane = threadIdx.x & 63, w = threadIdx.x >> 6;
#pragma unroll
    for (int o = 32; o > 0; o >>= 1) v = fmaxf(v, __shfl_down(v, o, 64));
    if (lane == 0) s[w] = v;
    __syncthreads();
    if (threadIdx.x == 0) tot = fmaxf(fmaxf(s[0], s[1]), fmaxf(s[2], s[3]));
    __syncthreads();
    return tot;
}

// out1 = (res?) res + rms(a)*(1+w1);   optionally out2 = rms(out1)*(1+w2)
__global__ void k_res_rms(const float* __restrict__ res,
                          const float* __restrict__ a,
                          const float* __restrict__ w1, float* __restrict__ out1,
                          const float* __restrict__ w2, float* __restrict__ out2) {
    const int K = D_ / 256;
    int t = threadIdx.x;
    float va[K];
    float ss = 0.f;
#pragma unroll
    for (int k = 0; k < K; k++) {
        int i = t + k * 256;
        va[k] = a[i];
        ss += va[k] * va[k];
    }
    float tot = block_red_sum(ss);
    float rs = rsqrtf(tot / (float)D_ + EPSF);
    float vo[K];
    float ss2 = 0.f;
#pragma unroll
    for (int k = 0; k < K; k++) {
        int i = t + k * 256;
        float r = res ? res[i] : 0.f;
        vo[k] = r + va[k] * rs * (1.f + w1[i]);
        out1[i] = vo[k];
        ss2 += vo[k] * vo[k];
    }
    if (out2) {
        float tot2 = block_red_sum(ss2);
        float rs2 = rsqrtf(tot2 / (float)D_ + EPSF);
#pragma unroll
        for (int k = 0; k < K; k++) {
            int i = t + k * 256;
            out2[i] = vo[k] * rs2 * (1.f + w2[i]);
        }
    }
}

// per-head q-norm (no weight) + RoPE.  grid = NH_, block = HD_ (=256)
__global__ void k_qnorm_rope(const float* __restrict__ qraw,
                             const float* __restrict__ cosv,
                             const float* __restrict__ sinv,
                             float* __restrict__ qout) {
    __shared__ float qn[HD_];
    int h = blockIdx.x, d = threadIdx.x;
    float v = qraw[h * HD_ + d];
    float tot = block_red_sum(v * v);
    float rs = rsqrtf(tot / (float)HD_ + EPSF);
    float n = v * rs;
    qn[d] = n;
    __syncthreads();
    float rot = (d < HD_ / 2) ? -qn[d + HD_ / 2] : qn[d - HD_ / 2];
    qout[h * HD_ + d] = n * cosv[d] + rot * sinv[d];
}

// y[row] = dot(W[row,:], x).  wave per row, x staged in LDS, weight chunks
// register-staged in fully-unrolled groups so 5-8 loads are in flight.
template <int COLS>
__global__ __launch_bounds__(256) void k_gemv(const float* __restrict__ W,
                                              const float* __restrict__ x,
                                              float* __restrict__ y, int rows) {
    constexpr int NC = COLS / 4;          // float4 chunks per row
    constexpr int CPL = NC / 64;          // chunks per lane
    constexpr int G = (CPL % 8 == 0) ? 8 : 5;   // group size (divides CPL)
    __shared__ float4 xs[NC];
    int t = threadIdx.x;
#pragma unroll
    for (int i = t; i < NC; i += 256) xs[i] = ((const float4*)x)[i];
    __syncthreads();
    int lane = t & 63;
    int row = blockIdx.x * 4 + (t >> 6);
    const float4* Wr = (const float4*)(W + (size_t)row * COLS);
    float acc = 0.f;
#pragma unroll
    for (int g0 = 0; g0 < CPL; g0 += G) {
        float4 w[G];
#pragma unroll
        for (int k = 0; k < G; k++) w[k] = Wr[lane + (g0 + k) * 64];
#pragma unroll
        for (int k = 0; k < G; k++) {
            float4 xx = xs[lane + (g0 + k) * 64];
            acc += w[k].x * xx.x + w[k].y * xx.y + w[k].z * xx.z + w[k].w * xx.w;
        }
    }
    acc = wave_red_sum(acc);
    if (lane == 0 && row < rows) y[row] = acc;
}

// scores for both q-heads of one kv head.  grid=(NKV_, LCHUNKS), block=256
__global__ void k_scores(const float* __restrict__ Kc, const float* __restrict__ q,
                         const float* __restrict__ mask, float* __restrict__ s) {
    int kvh = blockIdx.x, chunk = blockIdx.y;
    int lane = threadIdx.x & 63, w = threadIdx.x >> 6;
    int h0 = 2 * kvh, h1 = h0 + 1;
    const float4* q4 = (const float4*)q;
    float4 q0 = q4[h0 * 64 + lane];
    float4 q1 = q4[h1 * 64 + lane];
    int lbase = chunk * LCHUNK + w * 64;
    for (int i = 0; i < 64; i++) {
        int l = lbase + i;
        const float4* Kr = (const float4*)(Kc + ((size_t)kvh * CTX_ + l) * HD_);
        float4 kk = Kr[lane];
        float d0 = kk.x * q0.x + kk.y * q0.y + kk.z * q0.z + kk.w * q0.w;
        float d1 = kk.x * q1.x + kk.y * q1.y + kk.z * q1.z + kk.w * q1.w;
#pragma unroll
        for (int o = 32; o > 0; o >>= 1) {
            d0 += __shfl_down(d0, o, 64);
            d1 += __shfl_down(d1, o, 64);
        }
        if (lane == 0) {
            float m = mask[l];
            s[(size_t)h0 * CTX_ + l] = d0 + m;
            s[(size_t)h1 * CTX_ + l] = d1 + m;
        }
    }
}

// in-place softmax over CTX_ per head.  grid=NH_, block=256
__global__ void k_softmax(float* __restrict__ s) {
    int h = blockIdx.x, t = threadIdx.x;
    float* sh = s + (size_t)h * CTX_;
    float m = -1e30f;
    for (int l = t; l < CTX_; l += 256) m = fmaxf(m, sh[l]);
    m = block_red_max(m);
    float sum = 0.f;
    for (int l = t; l < CTX_; l += 256) {
        float e = expf(sh[l] - m);
        sh[l] = e;
        sum += e;
    }
    sum = block_red_sum(sum);
    float inv = 1.f / sum;
    for (int l = t; l < CTX_; l += 256) sh[l] *= inv;
}

// weighted V partials: V read once per kv head, used for both q heads.
__global__ void k_wv(const float* __restrict__ V, const float* __restrict__ p,
                     float* __restrict__ part) {
    int kvh = blockIdx.x, chunk = blockIdx.y, d = threadIdx.x;
    int h0 = 2 * kvh, h1 = h0 + 1;
    __shared__ float p0[LCHUNK], p1[LCHUNK];
    int l0 = chunk * LCHUNK;
    p0[d] = p[(size_t)h0 * CTX_ + l0 + d];
    p1[d] = p[(size_t)h1 * CTX_ + l0 + d];
    __syncthreads();
    const float* Vb = V + ((size_t)kvh * CTX_ + l0) * HD_;
    float a0 = 0.f, a1 = 0.f;
    for (int li = 0; li < LCHUNK; li++) {
        float v = Vb[(size_t)li * HD_ + d];
        a0 += p0[li] * v;
        a1 += p1[li] * v;
    }
    part[((h0 * LCHUNKS) + chunk) * HD_ + d] = a0;
    part[((h1 * LCHUNKS) + chunk) * HD_ + d] = a1;
}

// a[h*HD+d] = sum over chunks.  grid=NH_, block=HD_
__global__ void k_reduce_a(const float* __restrict__ part, float* __restrict__ a) {
    int h = blockIdx.x, d = threadIdx.x;
    float s = 0.f;
#pragma unroll
    for (int c = 0; c < LCHUNKS; c++) s += part[((h * LCHUNKS) + c) * HD_ + d];
    a[h * HD_ + d] = s;
}

// gu[row] = gelu_tanh(dot(Wg[row],h)) * dot(Wu[row],h).  wave per row.
// x staged in LDS; weight chunks register-staged in groups of 5 per stream
// (10 independent loads in flight per wave).
__global__ __launch_bounds__(256) void k_geglu(const float* __restrict__ Wg,
                                               const float* __restrict__ Wu,
                                               const float* __restrict__ h,
                                               float* __restrict__ gu) {
    constexpr int NC = D_ / 4;   // 640 chunks
    __shared__ float4 xs[NC];    // 10 KB
    int t = threadIdx.x;
#pragma unroll
    for (int i = t; i < NC; i += 256) xs[i] = ((const float4*)h)[i];
    __syncthreads();
    int lane = t & 63;
    int row = blockIdx.x * 4 + (t >> 6);
    const float4* g4 = (const float4*)(Wg + (size_t)row * D_);
    const float4* u4 = (const float4*)(Wu + (size_t)row * D_);
    float ag = 0.f, au = 0.f;
#pragma unroll
    for (int g0 = 0; g0 < 10; g0 += 5) {
        float4 wg[5], wu[5];
#pragma unroll
        for (int k = 0; k < 5; k++) wg[k] = g4[lane + (g0 + k) * 64];
#pragma unroll
        for (int k = 0; k < 5; k++) wu[k] = u4[lane + (g0 + k) * 64];
#pragma unroll
        for (int k = 0; k < 5; k++) {
            float4 xx = xs[lane + (g0 + k) * 64];
            ag += wg[k].x * xx.x + wg[k].y * xx.y + wg[k].z * xx.z + wg[k].w * xx.w;
            au += wu[k].x * xx.x + wu[k].y * xx.y + wu[k].z * xx.z + wu[k].w * xx.w;
        }
    }
#pragma unroll
    for (int o = 32; o > 0; o >>= 1) {
        ag += __shfl_down(ag, o, 64);
        au += __shfl_down(au, o, 64);
    }
    if (lane == 0) {
        float x = ag;
        float tt = tanhf(0.7978845608028654f * (x + 0.044715f * x * x * x));
        gu[row] = 0.5f * x * (1.f + tt) * au;
    }
}

extern "C" void kernel_launch(void* const* d_in, const int* in_sizes, int n_in,
                              void* d_out, int out_size, void* d_ws, size_t ws_size,
                              hipStream_t stream) {
    const float* x     = (const float*)d_in[0];
    const float* cosv  = (const float*)d_in[1];
    const float* sinv  = (const float*)d_in[2];
    const float* mask  = (const float*)d_in[3];
    const float* cK    = (const float*)d_in[4];
    const float* cV    = (const float*)d_in[5];
    // d_in[6] = ctx_len (== CTX_)
    const float* w_in  = (const float*)d_in[7];
    const float* w_pa  = (const float*)d_in[8];
    const float* w_pf  = (const float*)d_in[9];
    const float* w_pff = (const float*)d_in[10];
    const float* Wq    = (const float*)d_in[11];
    const float* Wo    = (const float*)d_in[12];
    const float* Wg    = (const float*)d_in[13];
    const float* Wu    = (const float*)d_in[14];
    const float* Wd    = (const float*)d_in[15];

    float* ws   = (float*)d_ws;
    float* h    = ws;           // 2560
    float* qraw = ws + 2560;    // 2048
    float* q    = ws + 4608;    // 2048
    float* sc   = ws + 6656;    // 8*4096 = 32768
    float* part = ws + 39424;   // 8*16*256 = 32768
    float* a    = ws + 72192;   // 2048
    float* ao   = ws + 74240;   // 2560
    float* x2   = ws + 76800;   // 2560
    float* h2   = ws + 79360;   // 2560
    float* gu   = ws + 81920;   // 10240
    float* ffn  = ws + 92160;   // 2560
    float* out  = (float*)d_out;

    // h = rmsnorm(x, w_in)
    k_res_rms<<<1, 256, 0, stream>>>(nullptr, x, w_in, h, nullptr, nullptr);
    // qraw = h @ Wq.T
    k_gemv<D_><<<QD_ / 4, 256, 0, stream>>>(Wq, h, qraw, QD_);
    // q = rope(qnorm(qraw))
    k_qnorm_rope<<<NH_, HD_, 0, stream>>>(qraw, cosv, sinv, q);
    // scores
    k_scores<<<dim3(NKV_, LCHUNKS), 256, 0, stream>>>(cK, q, mask, sc);
    // softmax in-place
    k_softmax<<<NH_, 256, 0, stream>>>(sc);
    // weighted V partials, then reduce to a
    k_wv<<<dim3(NKV_, LCHUNKS), HD_, 0, stream>>>(cV, sc, part);
    k_reduce_a<<<NH_, HD_, 0, stream>>>(part, a);
    // ao = a @ Wo.T
    k_gemv<QD_><<<D_ / 4, 256, 0, stream>>>(Wo, a, ao, D_);
    // x2 = x + rms(ao)*(1+w_pa);  h2 = rms(x2)*(1+w_pf)
    k_res_rms<<<1, 256, 0, stream>>>(x, ao, w_pa, x2, w_pf, h2);
    // gu = gelu(h2@Wg.T) * (h2@Wu.T)
    k_geglu<<<FFN_ / 4, 256, 0, stream>>>(Wg, Wu, h2, gu);
    // ffn = gu @ Wd.T
    k_gemv<FFN_><<<D_ / 4, 256, 0, stream>>>(Wd, gu, ffn, D_);
    // out = x2 + rms(ffn)*(1+w_pff)
    k_res_rms<<<1, 256, 0, stream>>>(x2, ffn, w_pff, out, nullptr, nullptr);
}